// Round 1
// baseline (259.774 us; speedup 1.0000x reference)
//
#include <hip/hip_runtime.h>
#include <math.h>

#define BB 8
#define DD 128
#define HWD 65536    // 256*256
#define BHW 524288   // 8*65536

__device__ __forceinline__ float warp_red_sum(float v) {
#pragma unroll
    for (int off = 32; off > 0; off >>= 1) v += __shfl_down(v, off, 64);
    return v;
}

// Classify the raw byte layout of the (originally bool) mask buffer.
// flag: 0=uint8, 1=int32, 2=float32, 3=int64
__global__ void detect_mask_kernel(const unsigned char* __restrict__ mb, int* flag_out) {
    __shared__ int any_gt1, any_m4, any_m84;
    if (threadIdx.x == 0) { any_gt1 = 0; any_m4 = 0; any_m84 = 0; }
    __syncthreads();
    int lg = 0, l4 = 0, l84 = 0;
    for (int i = threadIdx.x; i < 65536; i += blockDim.x) {
        unsigned char v = mb[i];
        if (v > 1) lg = 1;
        if (v && (i & 3)) l4 = 1;
        if (v && ((i & 7) == 4)) l84 = 1;
    }
    if (lg)  atomicOr(&any_gt1, 1);
    if (l4)  atomicOr(&any_m4, 1);
    if (l84) atomicOr(&any_m84, 1);
    __syncthreads();
    if (threadIdx.x == 0) {
        int f;
        if (any_gt1)      f = 2;   // float32 bytes (0x80/0x3f present)
        else if (any_m4)  f = 0;   // dense 0/1 bytes -> uint8/bool
        else if (any_m84) f = 1;   // nonzero only at 4-byte steps -> int32
        else              f = 3;   // only 8-byte steps (or all-false) -> int64
        *flag_out = f;
    }
}

__global__ __launch_bounds__(256)
void pixel_dino_main(const float* __restrict__ s_feats,
                     const float* __restrict__ t_feats,
                     const float* __restrict__ center,
                     const void*  __restrict__ mask,
                     const float* __restrict__ orig_x,
                     const int*   __restrict__ flag_p,
                     float* __restrict__ loss_sum,
                     float* __restrict__ cnt_sum) {
    const float TAU_T = 0.04f, TAU_S = 0.1f, EPSN = 1e-12f;
    const int lane = threadIdx.x & 63;
    const int wave = threadIdx.x >> 6;
    const int pix0 = blockIdx.x * 64;
    const int b    = pix0 >> 16;          // HWD = 2^16
    const int hw   = (pix0 & (HWD - 1)) + lane;
    const float* sp = s_feats + b * DD * HWD + hw;
    const float* tp = t_feats + b * DD * HWD + hw;
    const int d0 = wave * 32;

    float s_loc[32], t_loc[32];
    float ss = 0.f, tt = 0.f, smax = -1e30f, tmax = -1e30f;
#pragma unroll
    for (int k = 0; k < 32; ++k) {
        const int d = d0 + k;
        float sv = sp[d * HWD];
        float tv = tp[d * HWD] - center[d];
        s_loc[k] = sv; t_loc[k] = tv;
        ss += sv * sv; tt += tv * tv;
        smax = fmaxf(smax, sv);
        tmax = fmaxf(tmax, tv);
    }

    __shared__ float red[4][64][5];   // pad to 5: stride-5 floats kills 8-way conflicts
    red[wave][lane][0] = ss;   red[wave][lane][1] = tt;
    red[wave][lane][2] = smax; red[wave][lane][3] = tmax;
    __syncthreads();
    {
        const int p = threadIdx.x & 63, i = threadIdx.x >> 6;
        float v = red[0][p][i];
        if (i < 2) v = v + red[1][p][i] + red[2][p][i] + red[3][p][i];
        else       v = fmaxf(fmaxf(v, red[1][p][i]), fmaxf(red[2][p][i], red[3][p][i]));
        red[0][p][i] = v;
    }
    __syncthreads();
    const float ssT   = red[0][lane][0], ttT   = red[0][lane][1];
    const float smaxT = red[0][lane][2], tmaxT = red[0][lane][3];
    const float rs = 1.f / (fmaxf(sqrtf(ssT), EPSN) * TAU_S);
    const float rt = 1.f / (fmaxf(sqrtf(ttT), EPSN) * TAU_T);
    const float maxb = smaxT * rs;
    const float maxa = tmaxT * rt;

    float eb = 0.f, ea = 0.f, eab = 0.f;
#pragma unroll
    for (int k = 0; k < 32; ++k) {
        float bv = s_loc[k] * rs;
        float av = t_loc[k] * rt;
        float e1 = __expf(bv - maxb);
        float e2 = __expf(av - maxa);
        eb += e1; ea += e2; eab += e2 * bv;
    }
    __syncthreads();    // safe to reuse red
    red[wave][lane][0] = eb; red[wave][lane][1] = ea; red[wave][lane][2] = eab;
    __syncthreads();
    {
        const int p = threadIdx.x & 63, i = threadIdx.x >> 6;
        if (i < 3) red[0][p][i] = red[0][p][i] + red[1][p][i] + red[2][p][i] + red[3][p][i];
    }
    __syncthreads();

    if (wave == 0) {
        const float ebT = red[0][lane][0], eaT = red[0][lane][1], eabT = red[0][lane][2];
        float loss = maxb + __logf(ebT) - eabT / eaT;

        const int gidx = b * HWD + hw;
        const int flag = *flag_p;
        bool mval;
        if (flag == 0)      mval = ((const unsigned char*)mask)[gidx] != 0;
        else if (flag == 1) mval = ((const int*)mask)[gidx] != 0;
        else if (flag == 2) mval = ((const float*)mask)[gidx] != 0.f;
        else                mval = ((const long long*)mask)[gidx] != 0;
        const bool valid = (orig_x[gidx] != 0.f) && !mval;

        float l = valid ? loss : 0.f;
        float c = valid ? 1.f  : 0.f;
        l = warp_red_sum(l);
        c = warp_red_sum(c);
        if (lane == 0) {
            atomicAdd(&loss_sum[b], l);
            atomicAdd(&cnt_sum[b],  c);
        }
    }
}

__global__ void finalize_kernel(const float* __restrict__ loss_sum,
                                const float* __restrict__ cnt_sum,
                                float* __restrict__ out) {
    if (threadIdx.x == 0 && blockIdx.x == 0) {
        float acc = 0.f, nnz = 0.f, tot = 0.f;
        for (int b = 0; b < BB; ++b) {
            float c = cnt_sum[b];
            tot += c;
            if (c > 0.f) { acc += loss_sum[b] / c; nnz += 1.f; }
        }
        out[0] = (tot > 0.f) ? acc / fmaxf(nnz, 1.f) : 0.f;
    }
}

extern "C" void kernel_launch(void* const* d_in, const int* in_sizes, int n_in,
                              void* d_out, int out_size, void* d_ws, size_t ws_size,
                              hipStream_t stream) {
    const float* s_feats = (const float*)d_in[0];
    const float* t_feats = (const float*)d_in[1];
    const float* center  = (const float*)d_in[2];
    const void*  mask    = d_in[3];
    const float* orig_x  = (const float*)d_in[4];

    float* ws       = (float*)d_ws;
    int*   flag     = (int*)d_ws;     // ws[0]
    float* loss_sum = ws + 8;         // 8 floats
    float* cnt_sum  = ws + 16;        // 8 floats

    hipMemsetAsync(d_ws, 0, 128, stream);
    detect_mask_kernel<<<1, 256, 0, stream>>>((const unsigned char*)mask, flag);
    pixel_dino_main<<<BHW / 64, 256, 0, stream>>>(s_feats, t_feats, center, mask,
                                                  orig_x, flag, loss_sum, cnt_sum);
    finalize_kernel<<<1, 64, 0, stream>>>(loss_sum, cnt_sum, (float*)d_out);
}

// Round 2
// 110.009 us; speedup vs baseline: 2.3614x; 2.3614x over previous
//
#include <hip/hip_runtime.h>
#include <math.h>

#define BB 8
#define DD 128
#define HWD 65536    // 256*256
#define BHW 524288   // 8*65536

__device__ __forceinline__ float warp_red_sum(float v) {
#pragma unroll
    for (int off = 32; off > 0; off >>= 1) v += __shfl_down(v, off, 64);
    return v;
}

// Classify the raw byte layout of the (originally bool) mask buffer.
// flag: 0=uint8, 1=int32, 2=float32, 3=int64
// Scans first 64 KB (safe under every dtype interpretation; mask is dense
// bernoulli(0.5) so any-nonzero within the window is certain in practice).
__global__ void detect_mask_kernel(const uint4* __restrict__ mb, int* flag_out) {
    __shared__ int any_gt1, any_m4, any_m84;
    if (threadIdx.x == 0) { any_gt1 = 0; any_m4 = 0; any_m84 = 0; }
    __syncthreads();
    int lg = 0, l4 = 0, l84 = 0;
#pragma unroll
    for (int it = 0; it < 16; ++it) {
        const int i = it * 256 + threadIdx.x;   // 4096 uint4 = 64 KB
        uint4 w = mb[i];
        unsigned int anyw = w.x | w.y | w.z | w.w;
        if (anyw & 0xFEFEFEFEu) lg = 1;            // some byte > 1 -> float bits
        if (anyw & 0xFFFFFF00u) l4 = 1;            // nonzero byte at off%4 != 0
        if ((w.y | w.w) & 0xFFu) l84 = 1;          // nonzero byte at off%8 == 4
    }
    if (lg)  atomicOr(&any_gt1, 1);
    if (l4)  atomicOr(&any_m4, 1);
    if (l84) atomicOr(&any_m84, 1);
    __syncthreads();
    if (threadIdx.x == 0) {
        int f;
        if (any_gt1)      f = 2;   // float32
        else if (any_m4)  f = 0;   // dense 0/1 bytes -> uint8/bool
        else if (any_m84) f = 1;   // int32
        else              f = 3;   // int64 (or all-false: interpretation-invariant)
        *flag_out = f;
    }
}

// 512 threads = 8 waves. Wave w owns channels [16w, 16w+16); lane owns 2
// consecutive pixels (float2). Block covers 128 pixels x 128 channels.
__global__ __launch_bounds__(512, 4)
void pixel_dino_main(const float* __restrict__ s_feats,
                     const float* __restrict__ t_feats,
                     const float* __restrict__ center,
                     const void*  __restrict__ mask,
                     const float* __restrict__ orig_x,
                     const int*   __restrict__ flag_p,
                     float* __restrict__ loss_sum,
                     float* __restrict__ cnt_sum) {
    const float TAU_S_INV = 10.0f, TAU_T_INV = 25.0f, EPSN = 1e-12f;
    const int lane = threadIdx.x & 63;
    const int wave = threadIdx.x >> 6;
    const int b    = blockIdx.x >> 9;                      // 512 blocks/image
    const int hw   = ((blockIdx.x & 511) << 7) + (lane << 1);
    const float* sp = s_feats + (size_t)b * DD * HWD + hw;
    const float* tp = t_feats + (size_t)b * DD * HWD + hw;
    const int d0 = wave * 16;

    float2 sl[16], tl[16];
    float ssx = 0.f, ssy = 0.f, ttx = 0.f, tty = 0.f;
#pragma unroll
    for (int k = 0; k < 16; ++k) {
        const int d = d0 + k;
        float2 sv = *reinterpret_cast<const float2*>(sp + (size_t)d * HWD);
        float2 tv = *reinterpret_cast<const float2*>(tp + (size_t)d * HWD);
        const float c = center[d];
        tv.x -= c; tv.y -= c;
        sl[k] = sv; tl[k] = tv;
        ssx += sv.x * sv.x; ssy += sv.y * sv.y;
        ttx += tv.x * tv.x; tty += tv.y * tv.y;
    }
    // Forbid rematerialization of the global loads: pin values as VGPRs.
#pragma unroll
    for (int k = 0; k < 16; ++k) {
        asm volatile("" : "+v"(sl[k].x), "+v"(sl[k].y), "+v"(tl[k].x), "+v"(tl[k].y));
    }

    __shared__ float red[6][8][64];
    __shared__ float tot[6][64];
    red[0][wave][lane] = ssx; red[1][wave][lane] = ssy;
    red[2][wave][lane] = ttx; red[3][wave][lane] = tty;
    __syncthreads();
    if (threadIdx.x < 256) {                 // 4 quantities x 64 lanes
        const int q = threadIdx.x >> 6, l = threadIdx.x & 63;
        float v = 0.f;
#pragma unroll
        for (int w = 0; w < 8; ++w) v += red[q][w][l];
        tot[q][l] = v;
    }
    __syncthreads();

    const float rsx = TAU_S_INV / fmaxf(sqrtf(tot[0][lane]), EPSN);
    const float rsy = TAU_S_INV / fmaxf(sqrtf(tot[1][lane]), EPSN);
    const float rtx = TAU_T_INV / fmaxf(sqrtf(tot[2][lane]), EPSN);
    const float rty = TAU_T_INV / fmaxf(sqrtf(tot[3][lane]), EPSN);

    // No max-subtraction needed: |t_hat|/tau_t <= 25 -> exp <= 7.2e10 (fp32-safe).
    float ebx = 0.f, eby = 0.f, eax = 0.f, eay = 0.f, eabx = 0.f, eaby = 0.f;
#pragma unroll
    for (int k = 0; k < 16; ++k) {
        const float bvx = sl[k].x * rsx, bvy = sl[k].y * rsy;
        const float avx = tl[k].x * rtx, avy = tl[k].y * rty;
        const float e2x = __expf(avx),  e2y = __expf(avy);
        ebx += __expf(bvx); eby += __expf(bvy);
        eax += e2x;         eay += e2y;
        eabx += e2x * bvx;  eaby += e2y * bvy;
    }
    __syncthreads();
    red[0][wave][lane] = ebx;  red[1][wave][lane] = eby;
    red[2][wave][lane] = eax;  red[3][wave][lane] = eay;
    red[4][wave][lane] = eabx; red[5][wave][lane] = eaby;
    __syncthreads();
    if (threadIdx.x < 384) {                 // 6 quantities x 64 lanes
        const int q = threadIdx.x >> 6, l = threadIdx.x & 63;
        float v = 0.f;
#pragma unroll
        for (int w = 0; w < 8; ++w) v += red[q][w][l];
        tot[q][l] = v;
    }
    __syncthreads();

    if (wave == 0) {
        const float ebxT = tot[0][lane], ebyT = tot[1][lane];
        const float eaxT = tot[2][lane], eayT = tot[3][lane];
        const float eabxT = tot[4][lane], eabyT = tot[5][lane];
        const float lossx = __logf(ebxT) - eabxT / eaxT;
        const float lossy = __logf(ebyT) - eabyT / eayT;

        const int gidx = b * HWD + hw;
        const int flag = *flag_p;
        bool m0, m1;
        if (flag == 0) {
            const unsigned char* mm = (const unsigned char*)mask;
            m0 = mm[gidx] != 0; m1 = mm[gidx + 1] != 0;
        } else if (flag == 1) {
            const int* mm = (const int*)mask;
            m0 = mm[gidx] != 0; m1 = mm[gidx + 1] != 0;
        } else if (flag == 2) {
            const float* mm = (const float*)mask;
            m0 = mm[gidx] != 0.f; m1 = mm[gidx + 1] != 0.f;
        } else {
            const long long* mm = (const long long*)mask;
            m0 = mm[gidx] != 0; m1 = mm[gidx + 1] != 0;
        }
        const float2 ox = *reinterpret_cast<const float2*>(orig_x + gidx);
        const bool v0 = (ox.x != 0.f) && !m0;
        const bool v1 = (ox.y != 0.f) && !m1;

        float l = (v0 ? lossx : 0.f) + (v1 ? lossy : 0.f);
        float c = (v0 ? 1.f : 0.f) + (v1 ? 1.f : 0.f);
        l = warp_red_sum(l);
        c = warp_red_sum(c);
        if (lane == 0) {
            atomicAdd(&loss_sum[b], l);
            atomicAdd(&cnt_sum[b],  c);
        }
    }
}

__global__ void finalize_kernel(const float* __restrict__ loss_sum,
                                const float* __restrict__ cnt_sum,
                                float* __restrict__ out) {
    if (threadIdx.x == 0 && blockIdx.x == 0) {
        float acc = 0.f, nnz = 0.f, tot = 0.f;
        for (int b = 0; b < BB; ++b) {
            float c = cnt_sum[b];
            tot += c;
            if (c > 0.f) { acc += loss_sum[b] / c; nnz += 1.f; }
        }
        out[0] = (tot > 0.f) ? acc / fmaxf(nnz, 1.f) : 0.f;
    }
}

extern "C" void kernel_launch(void* const* d_in, const int* in_sizes, int n_in,
                              void* d_out, int out_size, void* d_ws, size_t ws_size,
                              hipStream_t stream) {
    const float* s_feats = (const float*)d_in[0];
    const float* t_feats = (const float*)d_in[1];
    const float* center  = (const float*)d_in[2];
    const void*  mask    = d_in[3];
    const float* orig_x  = (const float*)d_in[4];

    float* ws       = (float*)d_ws;
    int*   flag     = (int*)d_ws;     // ws[0]
    float* loss_sum = ws + 8;         // 8 floats
    float* cnt_sum  = ws + 16;        // 8 floats

    hipMemsetAsync(d_ws, 0, 128, stream);
    detect_mask_kernel<<<1, 256, 0, stream>>>((const uint4*)mask, flag);
    pixel_dino_main<<<BHW / 128, 512, 0, stream>>>(s_feats, t_feats, center, mask,
                                                   orig_x, flag, loss_sum, cnt_sum);
    finalize_kernel<<<1, 64, 0, stream>>>(loss_sum, cnt_sum, (float*)d_out);
}